// Round 4
// baseline (1326.872 us; speedup 1.0000x reference)
//
#include <hip/hip_runtime.h>
#include <hip/hip_bf16.h>

#define EPSBN 1e-5f
#define NGRAPH 512

struct f4 { float x, y, z, w; };
__device__ inline void f4add(f4& a, const float4& b) {
    a.x += b.x; a.y += b.y; a.z += b.z; a.w += b.w;
}
__device__ inline float f4c(const float4& v, int i) {
    return i == 0 ? v.x : i == 1 ? v.y : i == 2 ? v.z : v.w;
}

// ---------------------------------------------------------------------------
// CSR build step 1: histogram of dst
// ---------------------------------------------------------------------------
__global__ void __launch_bounds__(256) k_hist(
    const int* __restrict__ dst, int* __restrict__ hist, int E)
{
    for (int e = blockIdx.x * 256 + threadIdx.x; e < E; e += gridDim.x * 256)
        atomicAdd(&hist[dst[e]], 1);
}

// ---------------------------------------------------------------------------
// CSR build step 2: single-block exclusive prefix scan of hist
// ---------------------------------------------------------------------------
__global__ void __launch_bounds__(1024) k_scan(
    const int* __restrict__ hist, int* __restrict__ row_off,
    int* __restrict__ cursor, int N)
{
    __shared__ int part[1024];
    const int t = threadIdx.x;
    const int C = (N + 1023) / 1024;
    const int c0 = t * C;
    const int c1 = min(c0 + C, N);
    int s = 0;
    for (int i = c0; i < c1; i++) s += hist[i];
    part[t] = s;
    __syncthreads();
    for (int off = 1; off < 1024; off <<= 1) {
        int v = (t >= off) ? part[t - off] : 0;
        __syncthreads();
        part[t] += v;
        __syncthreads();
    }
    int run = part[t] - s;  // exclusive prefix
    for (int i = c0; i < c1; i++) {
        row_off[i] = run;
        cursor[i] = run;
        run += hist[i];
    }
    if (t == 0) row_off[N] = part[1023];
}

// ---------------------------------------------------------------------------
// CSR build step 3: scatter src ids into per-dst slots
// ---------------------------------------------------------------------------
__global__ void __launch_bounds__(256) k_scatter(
    const int* __restrict__ src, const int* __restrict__ dst,
    int* __restrict__ cursor, int* __restrict__ csr, int E)
{
    for (int e = blockIdx.x * 256 + threadIdx.x; e < E; e += gridDim.x * 256) {
        int d = dst[e];
        int p = atomicAdd(&cursor[d], 1);
        csr[p] = src[e];
    }
}

// ---------------------------------------------------------------------------
// Gather-aggregate: agg[i][:] = sum over neighbors s of feat[s][:]
// ---------------------------------------------------------------------------
template <int F>
__global__ void __launch_bounds__(256) k_gather(
    const float* __restrict__ feat, const int* __restrict__ row_off,
    const int* __restrict__ csr, float* __restrict__ agg, int N)
{
    constexpr int LPR = F / 4;        // lanes per row
    constexpr int RPB = 256 / LPR;    // rows per block
    const int lane = threadIdx.x % LPR;
    const int rloc = threadIdx.x / LPR;
    for (int row = blockIdx.x * RPB + rloc; row < N; row += gridDim.x * RPB) {
        const int s0 = row_off[row];
        const int s1 = row_off[row + 1];
        f4 acc0 = {0, 0, 0, 0}, acc1 = {0, 0, 0, 0};
        int p = s0;
        for (; p + 1 < s1; p += 2) {
            int sA = csr[p];
            int sB = csr[p + 1];
            f4add(acc0, *(const float4*)&feat[(long long)sA * F + lane * 4]);
            f4add(acc1, *(const float4*)&feat[(long long)sB * F + lane * 4]);
        }
        if (p < s1) {
            int sA = csr[p];
            f4add(acc0, *(const float4*)&feat[(long long)sA * F + lane * 4]);
        }
        float4 out;
        out.x = acc0.x + acc1.x; out.y = acc0.y + acc1.y;
        out.z = acc0.z + acc1.z; out.w = acc0.w + acc1.w;
        *(float4*)&agg[(long long)row * F + lane * 4] = out;
    }
}

// ---------------------------------------------------------------------------
// Wave-tile GEMM, zero LDS, no barriers.
// One wave = 64 rows x 16 cols. Lane owns one row x 16 cols in registers.
// W / affine / bias are wave-uniform scalar loads (readfirstlane'd jg).
//   acc  = xin_eff @ W        (xin_eff = AFFINE ? xin*a+c : xin)
//   DUAL:    acc += invc * (xin2 @ W2)       (layer-1 agg path)
//   HASBASE: acc += invc * base[row][j]      (layers 2/3 aggregated term)
//   FINAL:   v = relu(acc + bias); col sum/sumsq via shfl reduce + atomics
// ---------------------------------------------------------------------------
template <int FIN, int FOUT, bool DUAL, bool AFFINE, bool HASBASE, bool FINAL>
__global__ void __launch_bounds__(256) k_gemm(
    const float* __restrict__ xin,      // N x FIN
    const float* __restrict__ xin2,     // N x FIN (DUAL only)
    const float* __restrict__ a_in,     // FIN (AFFINE)
    const float* __restrict__ c_in,     // FIN (AFFINE)
    const float* __restrict__ W,        // FIN x FOUT
    const float* __restrict__ W2,       // FIN x FOUT (DUAL)
    const float* __restrict__ bias,     // FOUT (FINAL)
    const float* base,                  // N x FOUT (HASBASE; may alias out)
    const int* __restrict__ row_off,    // N+1
    float* out,                         // N x FOUT
    float* __restrict__ s_out, float* __restrict__ q_out,
    int N)
{
    constexpr int JG = FOUT / 16;
    const int lane = threadIdx.x & 63;
    int gw = blockIdx.x * 4 + (threadIdx.x >> 6);
    int rt = __builtin_amdgcn_readfirstlane(gw / JG);
    int jg = __builtin_amdgcn_readfirstlane(gw % JG);
    if (rt * 64 >= N) return;           // whole-wave OOB; no barriers used
    const int row = rt * 64 + lane;
    const bool valid = row < N;
    const int j0 = jg * 16;
    const long long xr = (long long)(valid ? row : rt * 64) * FIN;

    float invc = 1.f;
    if constexpr (DUAL || HASBASE) {
        if (valid) {
            int cnt = row_off[row + 1] - row_off[row];
            invc = 1.f / (float)max(cnt, 1);
        }
    }

    float acc[16];
    #pragma unroll
    for (int c = 0; c < 16; c++) acc[c] = 0.f;
    float acc2[DUAL ? 16 : 1];
    if constexpr (DUAL) {
        #pragma unroll
        for (int c = 0; c < 16; c++) acc2[c] = 0.f;
    }

    for (int k = 0; k < FIN; k += 4) {
        float4 xv = *(const float4*)&xin[xr + k];
        float4 x2v;
        if constexpr (DUAL) x2v = *(const float4*)&xin2[xr + k];
        #pragma unroll
        for (int kk = 0; kk < 4; kk++) {
            float xe = f4c(xv, kk);
            if constexpr (AFFINE) xe = fmaf(xe, a_in[k + kk], c_in[k + kk]);
            #pragma unroll
            for (int c = 0; c < 16; c++)
                acc[c] = fmaf(xe, W[(k + kk) * FOUT + j0 + c], acc[c]);
            if constexpr (DUAL) {
                float x2e = f4c(x2v, kk);
                #pragma unroll
                for (int c = 0; c < 16; c++)
                    acc2[c] = fmaf(x2e, W2[(k + kk) * FOUT + j0 + c], acc2[c]);
            }
        }
    }

    const long long o = (long long)row * FOUT + j0;
    float v[16];
    if constexpr (HASBASE) {
        #pragma unroll
        for (int c4 = 0; c4 < 16; c4 += 4) {
            float4 b4 = valid ? *(const float4*)&base[o + c4]
                              : make_float4(0.f, 0.f, 0.f, 0.f);
            acc[c4 + 0] = fmaf(invc, b4.x, acc[c4 + 0]);
            acc[c4 + 1] = fmaf(invc, b4.y, acc[c4 + 1]);
            acc[c4 + 2] = fmaf(invc, b4.z, acc[c4 + 2]);
            acc[c4 + 3] = fmaf(invc, b4.w, acc[c4 + 3]);
        }
    }
    #pragma unroll
    for (int c = 0; c < 16; c++) {
        float t = acc[c];
        if constexpr (DUAL) t = fmaf(invc, acc2[c], t);
        if constexpr (FINAL) t = fmaxf(t + bias[j0 + c], 0.f);
        v[c] = valid ? t : 0.f;
    }
    if (valid) {
        #pragma unroll
        for (int c4 = 0; c4 < 16; c4 += 4) {
            float4 o4 = make_float4(v[c4], v[c4 + 1], v[c4 + 2], v[c4 + 3]);
            *(float4*)&out[o + c4] = o4;
        }
    }

    if constexpr (FINAL) {
        #pragma unroll
        for (int c = 0; c < 16; c++) {
            float s = v[c];
            float q = v[c] * v[c];
            #pragma unroll
            for (int off = 32; off; off >>= 1) {
                s += __shfl_xor(s, off, 64);
                q += __shfl_xor(q, off, 64);
            }
            if (lane == 0) {
                atomicAdd(&s_out[j0 + c], s);
                atomicAdd(&q_out[j0 + c], q);
            }
        }
    }
}

// ---------------------------------------------------------------------------
// BN affine finalize: a = g / sqrt(var+eps), c = be - mu*a
// ---------------------------------------------------------------------------
__global__ void k_finalize(const float* __restrict__ s, const float* __restrict__ q,
                           const float* __restrict__ g, const float* __restrict__ be,
                           float* __restrict__ a, float* __restrict__ c,
                           int F, float invN)
{
    int j = threadIdx.x;
    if (j < F) {
        float mu = s[j] * invN;
        float var = q[j] * invN - mu * mu;
        float aj = g[j] / sqrtf(var + EPSBN);
        a[j] = aj;
        c[j] = be[j] - mu * aj;
    }
}

// ---------------------------------------------------------------------------
// pooled[batch[i]][j] += t3[i][j]*a[j] + c[j]
// ---------------------------------------------------------------------------
__global__ void __launch_bounds__(256) k_pool(
    const float* __restrict__ t3, const float* __restrict__ a,
    const float* __restrict__ c, const int* __restrict__ batch,
    float* __restrict__ pooled, int N)
{
    long long gid = (long long)blockIdx.x * 256 + threadIdx.x;
    int i = (int)(gid >> 5);
    int j = (int)(gid & 31);
    if (i >= N) return;
    int g = batch[i];
    float v = t3[(long long)i * 32 + j] * a[j] + c[j];
    atomicAdd(&pooled[g * 32 + j], v);
}

// ---------------------------------------------------------------------------
// Per-graph MLP: 32 -> 128 relu -> 64 relu -> 2. One block per graph.
// ---------------------------------------------------------------------------
__global__ void __launch_bounds__(128) k_mlp(
    const float* __restrict__ pooled,
    const float* __restrict__ Wf1, const float* __restrict__ bf1,
    const float* __restrict__ Wf2, const float* __restrict__ bf2,
    const float* __restrict__ Wf3, const float* __restrict__ bf3,
    float* __restrict__ out)
{
    __shared__ float p[32], h1[128], h2[64];
    int g = blockIdx.x, t = threadIdx.x;
    if (t < 32) p[t] = pooled[g * 32 + t];
    __syncthreads();
    {
        float acc = bf1[t];
        #pragma unroll
        for (int k = 0; k < 32; k++) acc += p[k] * Wf1[k * 128 + t];
        h1[t] = fmaxf(acc, 0.f);
    }
    __syncthreads();
    if (t < 64) {
        float acc = bf2[t];
        #pragma unroll
        for (int k = 0; k < 128; k++) acc += h1[k] * Wf2[k * 64 + t];
        h2[t] = fmaxf(acc, 0.f);
    }
    __syncthreads();
    if (t < 2) {
        float acc = bf3[t];
        #pragma unroll
        for (int k = 0; k < 64; k++) acc += h2[k] * Wf3[k * 2 + t];
        out[g * 2 + t] = acc;
    }
}

// ---------------------------------------------------------------------------
extern "C" void kernel_launch(void* const* d_in, const int* in_sizes, int n_in,
                              void* d_out, int out_size, void* d_ws, size_t ws_size,
                              hipStream_t stream)
{
    const float* x     = (const float*)d_in[0];
    const int*   ei    = (const int*)d_in[1];
    const int*   batch = (const int*)d_in[2];
    const float* W1l = (const float*)d_in[3];
    const float* b1  = (const float*)d_in[4];
    const float* W1r = (const float*)d_in[5];
    const float* g1  = (const float*)d_in[6];
    const float* be1 = (const float*)d_in[7];
    const float* W2l = (const float*)d_in[8];
    const float* b2  = (const float*)d_in[9];
    const float* W2r = (const float*)d_in[10];
    const float* g2  = (const float*)d_in[11];
    const float* be2 = (const float*)d_in[12];
    const float* W3l = (const float*)d_in[13];
    const float* b3  = (const float*)d_in[14];
    const float* W3r = (const float*)d_in[15];
    const float* g3  = (const float*)d_in[16];
    const float* be3 = (const float*)d_in[17];
    const float* Wf1 = (const float*)d_in[18];
    const float* bf1 = (const float*)d_in[19];
    const float* Wf2 = (const float*)d_in[20];
    const float* bf2 = (const float*)d_in[21];
    const float* Wf3 = (const float*)d_in[22];
    const float* bf3 = (const float*)d_in[23];

    const int N = in_sizes[0] / 64;
    const int E = in_sizes[1] / 2;
    const int* src = ei;
    const int* dst = ei + E;

    // ---- workspace layout (with aliasing) ----
    char* ws = (char*)d_ws;
    size_t off = 0;
    auto alloc = [&](size_t bytes) {
        size_t o = off;
        off += (bytes + 511) & ~(size_t)511;
        return o;
    };
    const size_t o_rowoff = alloc((size_t)(N + 1) * 4);
    const size_t o_hist   = alloc((size_t)N * 4);
    const size_t o_cursor = alloc((size_t)N * 4);
    const size_t o_csr    = alloc((size_t)E * 4);
    const size_t o_agg1   = alloc((size_t)N * 64 * 4);   // agg1 -> m2 -> t2
    const size_t o_t1     = alloc((size_t)N * 128 * 4);  // t1
    const size_t o_y2     = alloc((size_t)N * 64 * 4);   // y2; then y3 | m3->t3
    const size_t o_pool   = alloc((size_t)NGRAPH * 32 * 4);
    const size_t o_stats  = alloc(448 * 4);
    const size_t o_aff    = alloc(448 * 4);
    (void)ws_size;

    int* row_off = (int*)(ws + o_rowoff);
    int* hist    = (int*)(ws + o_hist);
    int* cursor  = (int*)(ws + o_cursor);
    int* csr     = (int*)(ws + o_csr);
    float* agg1 = (float*)(ws + o_agg1);
    float* m2   = agg1;                       // alias (gather overwrites fully)
    float* t2   = m2;                         // in-place epilogue overwrite
    float* t1   = (float*)(ws + o_t1);
    float* y2   = (float*)(ws + o_y2);
    float* y3   = y2;                         // N x 32, y2 dead after gather
    float* m3   = y2 + (size_t)N * 32;
    float* t3   = m3;                         // in-place epilogue overwrite
    float* pooled = (float*)(ws + o_pool);
    float* s1 = (float*)(ws + o_stats);
    float* q1 = s1 + 128;
    float* s2 = q1 + 128;
    float* q2 = s2 + 64;
    float* s3 = q2 + 64;
    float* q3 = s3 + 32;
    float* a1 = (float*)(ws + o_aff);
    float* c1 = a1 + 128;
    float* a2 = c1 + 128;
    float* c2 = a2 + 64;
    float* a3 = c2 + 64;
    float* c3 = a3 + 32;

    const float invN = 1.0f / (float)N;
    const int RT = (N + 63) / 64;             // 64-row tiles
    auto blk = [&](int jg) { return (RT * jg + 3) / 4; };

    // ---- zero accumulators ----
    hipMemsetAsync(ws + o_hist, 0, (size_t)N * 4, stream);
    hipMemsetAsync(ws + o_stats, 0, 448 * 4, stream);
    hipMemsetAsync(ws + o_pool, 0, (size_t)NGRAPH * 32 * 4, stream);

    // ---- CSR build (amortized over 3 aggregations) ----
    k_hist<<<2048, 256, 0, stream>>>(dst, hist, E);
    k_scan<<<1, 1024, 0, stream>>>(hist, row_off, cursor, N);
    k_scatter<<<2048, 256, 0, stream>>>(src, dst, cursor, csr, E);

    // ---- layer 1 (dual-K fused: t1 = relu(x@W1r + (agg1/cnt)@W1l + b1)) ----
    k_gather<64><<<(N + 15) / 16, 256, 0, stream>>>(x, row_off, csr, agg1, N);
    k_gemm<64, 128, true, false, false, true><<<blk(8), 256, 0, stream>>>(
        x, agg1, nullptr, nullptr, W1r, W1l, b1, nullptr, row_off,
        t1, s1, q1, N);
    k_finalize<<<1, 128, 0, stream>>>(s1, q1, g1, be1, a1, c1, 128, invN);

    // ---- layer 2 (transform-first aggregation) ----
    // y2 = (t1*a1+c1) @ W2l
    k_gemm<128, 64, false, true, false, false><<<blk(4), 256, 0, stream>>>(
        t1, nullptr, a1, c1, W2l, nullptr, nullptr, nullptr, row_off,
        y2, nullptr, nullptr, N);
    k_gather<64><<<(N + 15) / 16, 256, 0, stream>>>(y2, row_off, csr, m2, N);
    // t2 = relu((t1*a1+c1) @ W2r + m2/cnt + b2)   [in place over m2]
    k_gemm<128, 64, false, true, true, true><<<blk(4), 256, 0, stream>>>(
        t1, nullptr, a1, c1, W2r, nullptr, b2, m2, row_off,
        t2, s2, q2, N);
    k_finalize<<<1, 64, 0, stream>>>(s2, q2, g2, be2, a2, c2, 64, invN);

    // ---- layer 3 ----
    k_gemm<64, 32, false, true, false, false><<<blk(2), 256, 0, stream>>>(
        t2, nullptr, a2, c2, W3l, nullptr, nullptr, nullptr, row_off,
        y3, nullptr, nullptr, N);
    k_gather<32><<<(N + 31) / 32, 256, 0, stream>>>(y3, row_off, csr, m3, N);
    k_gemm<64, 32, false, true, true, true><<<blk(2), 256, 0, stream>>>(
        t2, nullptr, a2, c2, W3r, nullptr, b3, m3, row_off,
        t3, s3, q3, N);
    k_finalize<<<1, 32, 0, stream>>>(s3, q3, g3, be3, a3, c3, 32, invN);

    // ---- pool + MLP ----
    {
        long long tot = (long long)N * 32;
        int blocks = (int)((tot + 255) / 256);
        k_pool<<<blocks, 256, 0, stream>>>(t3, a3, c3, batch, pooled, N);
    }
    k_mlp<<<NGRAPH, 128, 0, stream>>>(pooled, Wf1, bf1, Wf2, bf2, Wf3, bf3,
                                      (float*)d_out);
}

// Round 5
// 456.968 us; speedup vs baseline: 2.9036x; 2.9036x over previous
//
#include <hip/hip_runtime.h>
#include <hip/hip_bf16.h>

#define EPSBN 1e-5f
#define NGRAPH 512

typedef __attribute__((ext_vector_type(8))) short bf16x8;
typedef __attribute__((ext_vector_type(4))) float f32x4;

struct f4 { float x, y, z, w; };
__device__ inline void f4add(f4& a, const float4& b) {
    a.x += b.x; a.y += b.y; a.z += b.z; a.w += b.w;
}
__device__ inline short f2bf(float f) {  // RNE float->bf16
    unsigned u = __builtin_bit_cast(unsigned, f);
    u += 0x7fffu + ((u >> 16) & 1u);
    return (short)(u >> 16);
}

// ---------------------------------------------------------------------------
// CSR build
// ---------------------------------------------------------------------------
__global__ void __launch_bounds__(256) k_hist(
    const int* __restrict__ dst, int* __restrict__ hist, int E)
{
    for (int e = blockIdx.x * 256 + threadIdx.x; e < E; e += gridDim.x * 256)
        atomicAdd(&hist[dst[e]], 1);
}

__global__ void __launch_bounds__(1024) k_scan(
    const int* __restrict__ hist, int* __restrict__ row_off,
    int* __restrict__ cursor, int N)
{
    __shared__ int part[1024];
    const int t = threadIdx.x;
    const int C = (N + 1023) / 1024;
    const int c0 = t * C;
    const int c1 = min(c0 + C, N);
    int s = 0;
    for (int i = c0; i < c1; i++) s += hist[i];
    part[t] = s;
    __syncthreads();
    for (int off = 1; off < 1024; off <<= 1) {
        int v = (t >= off) ? part[t - off] : 0;
        __syncthreads();
        part[t] += v;
        __syncthreads();
    }
    int run = part[t] - s;
    for (int i = c0; i < c1; i++) {
        row_off[i] = run;
        cursor[i] = run;
        run += hist[i];
    }
    if (t == 0) row_off[N] = part[1023];
}

__global__ void __launch_bounds__(256) k_scatter(
    const int* __restrict__ src, const int* __restrict__ dst,
    int* __restrict__ cursor, int* __restrict__ csr, int E)
{
    for (int e = blockIdx.x * 256 + threadIdx.x; e < E; e += gridDim.x * 256) {
        int d = dst[e];
        int p = atomicAdd(&cursor[d], 1);
        csr[p] = src[e];
    }
}

// ---------------------------------------------------------------------------
// Gather-aggregate (fp32 in, fp32 or bf16 out)
// ---------------------------------------------------------------------------
template <int F, bool OB>
__global__ void __launch_bounds__(256) k_gather(
    const float* __restrict__ feat, const int* __restrict__ row_off,
    const int* __restrict__ csr, void* __restrict__ aggv, int N)
{
    constexpr int LPR = F / 4;
    constexpr int RPB = 256 / LPR;
    const int lane = threadIdx.x % LPR;
    const int rloc = threadIdx.x / LPR;
    float* aggf = (float*)aggv;
    short* aggb = (short*)aggv;
    for (int row = blockIdx.x * RPB + rloc; row < N; row += gridDim.x * RPB) {
        const int s0 = row_off[row];
        const int s1 = row_off[row + 1];
        f4 acc0 = {0, 0, 0, 0}, acc1 = {0, 0, 0, 0};
        int p = s0;
        for (; p + 1 < s1; p += 2) {
            int sA = csr[p];
            int sB = csr[p + 1];
            f4add(acc0, *(const float4*)&feat[(long long)sA * F + lane * 4]);
            f4add(acc1, *(const float4*)&feat[(long long)sB * F + lane * 4]);
        }
        if (p < s1) {
            int sA = csr[p];
            f4add(acc0, *(const float4*)&feat[(long long)sA * F + lane * 4]);
        }
        float ox = acc0.x + acc1.x, oy = acc0.y + acc1.y;
        float oz = acc0.z + acc1.z, ow = acc0.w + acc1.w;
        if constexpr (OB) {
            short4 o = make_short4(f2bf(ox), f2bf(oy), f2bf(oz), f2bf(ow));
            *(short4*)&aggb[(long long)row * F + lane * 4] = o;
        } else {
            float4 o = make_float4(ox, oy, oz, ow);
            *(float4*)&aggf[(long long)row * F + lane * 4] = o;
        }
    }
}

// ---------------------------------------------------------------------------
// fp32 -> bf16 convert
// ---------------------------------------------------------------------------
__global__ void __launch_bounds__(256) k_cvt(
    const float* __restrict__ in, short* __restrict__ out, long long n4)
{
    long long i = (long long)blockIdx.x * 256 + threadIdx.x;
    if (i >= n4) return;
    float4 v = *(const float4*)&in[i * 4];
    short4 o = make_short4(f2bf(v.x), f2bf(v.y), f2bf(v.z), f2bf(v.w));
    *(short4*)&out[i * 4] = o;
}

// ---------------------------------------------------------------------------
// Weight prep: Wt[j][k] = bf16(a[k]*W[k][j]); cvec[j] = sum_k c[k]*W[k][j] + bias[j]
// ---------------------------------------------------------------------------
template <int K, int F, bool AFF>
__global__ void __launch_bounds__(64) k_wprep(
    const float* __restrict__ W, const float* __restrict__ a,
    const float* __restrict__ c, const float* __restrict__ bias,
    short* __restrict__ Wt, float* __restrict__ cvec)
{
    int j = blockIdx.x * 64 + threadIdx.x;
    if (j >= F) return;
    float cv = bias ? bias[j] : 0.f;
    for (int k = 0; k < K; k++) {
        float w = W[k * F + j];
        float aa = 1.f;
        if constexpr (AFF) {
            aa = a[k];
            cv += c[k] * w;
        }
        Wt[j * K + k] = f2bf(aa * w);
    }
    cvec[j] = cv;
}

// ---------------------------------------------------------------------------
// MFMA bf16 GEMM with fused epilogue.
//   out = [relu]( A@Wt' + DUAL*invc*(A2@Wt2') + HASBASE*invc*base + cvec )
// Layouts (mfma_f32_16x16x32_bf16, m89-verified):
//   A-frag: row = lane&15, k = 8*(lane>>4)+e   (row-major A, 16B/lane)
//   B-frag: col = lane&15, k = 8*(lane>>4)+e   (Wt stored [FOUT][K], 16B/lane)
//   D:      col = lane&15, row = 4*(lane>>4)+r
// Wave owns a 16-row tile; A-frags in registers across all col-tiles.
// ---------------------------------------------------------------------------
template <int K, int FOUT, bool DUAL, bool HASBASE, bool FINAL, bool OUTBF16>
__global__ void __launch_bounds__(256) k_mgemm(
    const short* __restrict__ A, const short* __restrict__ A2,
    const short* __restrict__ Wt, const short* __restrict__ Wt2,
    const float* __restrict__ cvec, const float* __restrict__ base,
    const int* __restrict__ row_off, void* outv,
    float* __restrict__ s_out, float* __restrict__ q_out, int N)
{
    constexpr int KS = K / 32;
    constexpr int NCT = FOUT / 16;
    const int lane = threadIdx.x & 63;
    const int wid = threadIdx.x >> 6;
    const int g = lane >> 4;
    const int mi = lane & 15;
    const int RT = (N + 15) >> 4;
    const int nw = gridDim.x * 4;
    float* outf = (float*)outv;
    short* outb = (short*)outv;

    float st_s[FINAL ? NCT : 1];
    float st_q[FINAL ? NCT : 1];
    if constexpr (FINAL) {
        #pragma unroll
        for (int ct = 0; ct < NCT; ct++) { st_s[ct] = 0.f; st_q[ct] = 0.f; }
    }

    for (int rt = blockIdx.x * 4 + wid; rt < RT; rt += nw) {
        const int m0 = rt * 16;
        int arow = m0 + mi;
        if (arow >= N) arow = N - 1;

        bf16x8 af[KS];
        bf16x8 af2[DUAL ? KS : 1];
        const short* ap = A + (long long)arow * K;
        #pragma unroll
        for (int s = 0; s < KS; s++)
            af[s] = *(const bf16x8*)(ap + s * 32 + g * 8);
        if constexpr (DUAL) {
            const short* ap2 = A2 + (long long)arow * K;
            #pragma unroll
            for (int s = 0; s < KS; s++)
                af2[s] = *(const bf16x8*)(ap2 + s * 32 + g * 8);
        }

        float invc[4];
        if constexpr (DUAL || HASBASE) {
            #pragma unroll
            for (int r = 0; r < 4; r++) {
                int row = m0 + 4 * g + r;
                int cnt = 1;
                if (row < N) cnt = max(row_off[row + 1] - row_off[row], 1);
                invc[r] = 1.f / (float)cnt;
            }
        }

        #pragma unroll
        for (int ct = 0; ct < NCT; ct++) {
            f32x4 acc = {0.f, 0.f, 0.f, 0.f};
            f32x4 acc2 = {0.f, 0.f, 0.f, 0.f};
            const short* bp = Wt + (long long)(ct * 16 + mi) * K;
            #pragma unroll
            for (int s = 0; s < KS; s++) {
                bf16x8 bf = *(const bf16x8*)(bp + s * 32 + g * 8);
                acc = __builtin_amdgcn_mfma_f32_16x16x32_bf16(af[s], bf, acc, 0, 0, 0);
                if constexpr (DUAL) {
                    bf16x8 bf2 = *(const bf16x8*)(Wt2 + (long long)(ct * 16 + mi) * K + s * 32 + g * 8);
                    acc2 = __builtin_amdgcn_mfma_f32_16x16x32_bf16(af2[s], bf2, acc2, 0, 0, 0);
                }
            }
            float cv = cvec[ct * 16 + mi];
            float sl = 0.f, ql = 0.f;
            #pragma unroll
            for (int r = 0; r < 4; r++) {
                int row = m0 + 4 * g + r;
                if (row < N) {
                    float v = acc[r] + cv;
                    if constexpr (DUAL) v = fmaf(invc[r], acc2[r], v);
                    if constexpr (HASBASE)
                        v = fmaf(invc[r], base[(long long)row * FOUT + ct * 16 + mi], v);
                    if constexpr (FINAL) v = fmaxf(v, 0.f);
                    if constexpr (OUTBF16)
                        outb[(long long)row * FOUT + ct * 16 + mi] = f2bf(v);
                    else
                        outf[(long long)row * FOUT + ct * 16 + mi] = v;
                    if constexpr (FINAL) { sl += v; ql += v * v; }
                }
            }
            if constexpr (FINAL) {
                sl += __shfl_xor(sl, 16, 64);
                sl += __shfl_xor(sl, 32, 64);
                ql += __shfl_xor(ql, 16, 64);
                ql += __shfl_xor(ql, 32, 64);
                st_s[ct] += sl;
                st_q[ct] += ql;
            }
        }
    }

    if constexpr (FINAL) {
        __shared__ float redS[4][NCT][16];
        __shared__ float redQ[4][NCT][16];
        if (lane < 16) {
            #pragma unroll
            for (int ct = 0; ct < NCT; ct++) {
                redS[wid][ct][lane] = st_s[ct];
                redQ[wid][ct][lane] = st_q[ct];
            }
        }
        __syncthreads();
        if (wid == 0 && lane < 16) {
            #pragma unroll
            for (int ct = 0; ct < NCT; ct++) {
                float s = redS[0][ct][lane] + redS[1][ct][lane] +
                          redS[2][ct][lane] + redS[3][ct][lane];
                float q = redQ[0][ct][lane] + redQ[1][ct][lane] +
                          redQ[2][ct][lane] + redQ[3][ct][lane];
                atomicAdd(&s_out[ct * 16 + lane], s);
                atomicAdd(&q_out[ct * 16 + lane], q);
            }
        }
    }
}

// ---------------------------------------------------------------------------
// BN affine finalize
// ---------------------------------------------------------------------------
__global__ void k_finalize(const float* __restrict__ s, const float* __restrict__ q,
                           const float* __restrict__ g, const float* __restrict__ be,
                           float* __restrict__ a, float* __restrict__ c,
                           int F, float invN)
{
    int j = threadIdx.x;
    if (j < F) {
        float mu = s[j] * invN;
        float var = q[j] * invN - mu * mu;
        float aj = g[j] / sqrtf(var + EPSBN);
        a[j] = aj;
        c[j] = be[j] - mu * aj;
    }
}

// ---------------------------------------------------------------------------
// pooled[batch[i]][j] += t3[i][j]*a[j] + c[j]
// ---------------------------------------------------------------------------
__global__ void __launch_bounds__(256) k_pool(
    const float* __restrict__ t3, const float* __restrict__ a,
    const float* __restrict__ c, const int* __restrict__ batch,
    float* __restrict__ pooled, int N)
{
    long long gid = (long long)blockIdx.x * 256 + threadIdx.x;
    int i = (int)(gid >> 5);
    int j = (int)(gid & 31);
    if (i >= N) return;
    int g = batch[i];
    float v = t3[(long long)i * 32 + j] * a[j] + c[j];
    atomicAdd(&pooled[g * 32 + j], v);
}

// ---------------------------------------------------------------------------
// Per-graph MLP
// ---------------------------------------------------------------------------
__global__ void __launch_bounds__(128) k_mlp(
    const float* __restrict__ pooled,
    const float* __restrict__ Wf1, const float* __restrict__ bf1,
    const float* __restrict__ Wf2, const float* __restrict__ bf2,
    const float* __restrict__ Wf3, const float* __restrict__ bf3,
    float* __restrict__ out)
{
    __shared__ float p[32], h1[128], h2[64];
    int g = blockIdx.x, t = threadIdx.x;
    if (t < 32) p[t] = pooled[g * 32 + t];
    __syncthreads();
    {
        float acc = bf1[t];
        #pragma unroll
        for (int k = 0; k < 32; k++) acc += p[k] * Wf1[k * 128 + t];
        h1[t] = fmaxf(acc, 0.f);
    }
    __syncthreads();
    if (t < 64) {
        float acc = bf2[t];
        #pragma unroll
        for (int k = 0; k < 128; k++) acc += h1[k] * Wf2[k * 64 + t];
        h2[t] = fmaxf(acc, 0.f);
    }
    __syncthreads();
    if (t < 2) {
        float acc = bf3[t];
        #pragma unroll
        for (int k = 0; k < 64; k++) acc += h2[k] * Wf3[k * 2 + t];
        out[g * 2 + t] = acc;
    }
}

// ---------------------------------------------------------------------------
extern "C" void kernel_launch(void* const* d_in, const int* in_sizes, int n_in,
                              void* d_out, int out_size, void* d_ws, size_t ws_size,
                              hipStream_t stream)
{
    const float* x     = (const float*)d_in[0];
    const int*   ei    = (const int*)d_in[1];
    const int*   batch = (const int*)d_in[2];
    const float* W1l = (const float*)d_in[3];
    const float* b1  = (const float*)d_in[4];
    const float* W1r = (const float*)d_in[5];
    const float* g1  = (const float*)d_in[6];
    const float* be1 = (const float*)d_in[7];
    const float* W2l = (const float*)d_in[8];
    const float* b2  = (const float*)d_in[9];
    const float* W2r = (const float*)d_in[10];
    const float* g2  = (const float*)d_in[11];
    const float* be2 = (const float*)d_in[12];
    const float* W3l = (const float*)d_in[13];
    const float* b3  = (const float*)d_in[14];
    const float* W3r = (const float*)d_in[15];
    const float* g3  = (const float*)d_in[16];
    const float* be3 = (const float*)d_in[17];
    const float* Wf1 = (const float*)d_in[18];
    const float* bf1 = (const float*)d_in[19];
    const float* Wf2 = (const float*)d_in[20];
    const float* bf2 = (const float*)d_in[21];
    const float* Wf3 = (const float*)d_in[22];
    const float* bf3 = (const float*)d_in[23];

    const int N = in_sizes[0] / 64;
    const int E = in_sizes[1] / 2;
    const int* src = ei;
    const int* dst = ei + E;

    // ---- workspace layout (zoned aliasing) ----
    char* ws = (char*)d_ws;
    size_t off = 0;
    auto alloc = [&](size_t bytes) {
        size_t o = off;
        off += (bytes + 511) & ~(size_t)511;
        return o;
    };
    const size_t o_rowoff = alloc((size_t)(N + 1) * 4);
    const size_t o_hist   = alloc((size_t)N * 4);
    const size_t o_cursor = alloc((size_t)N * 4);
    const size_t o_csr    = alloc((size_t)E * 4);
    const size_t o_zoneB  = alloc((size_t)N * 128);  // xb (bf16) -> t2b (bf16)
    const size_t o_zoneC  = alloc((size_t)N * 128);  // aggb (bf16) -> y3 (fp32)
    const size_t o_zoneD  = alloc((size_t)N * 256);  // t1b (bf16) -> m3|t3 (fp32)
    const size_t o_y2     = alloc((size_t)N * 256);  // fp32
    const size_t o_m2     = alloc((size_t)N * 256);  // fp32
    const size_t o_pool   = alloc((size_t)NGRAPH * 32 * 4);
    const size_t o_stats  = alloc(448 * 4);
    const size_t o_aff    = alloc(448 * 4);
    const size_t o_cvec   = alloc(512 * 4);
    const size_t o_wt     = alloc((8192 * 4 + 2048 * 2) * 2);
    (void)ws_size;

    int* row_off = (int*)(ws + o_rowoff);
    int* hist    = (int*)(ws + o_hist);
    int* cursor  = (int*)(ws + o_cursor);
    int* csr     = (int*)(ws + o_csr);
    short* xb   = (short*)(ws + o_zoneB);
    short* t2b  = (short*)(ws + o_zoneB);       // after xb dead
    short* aggb = (short*)(ws + o_zoneC);
    float* y3   = (float*)(ws + o_zoneC);       // after aggb dead
    short* t1b  = (short*)(ws + o_zoneD);
    float* m3   = (float*)(ws + o_zoneD);       // after t1b dead
    float* t3   = (float*)(ws + o_zoneD + (size_t)N * 128);
    float* y2   = (float*)(ws + o_y2);
    float* m2   = (float*)(ws + o_m2);
    float* pooled = (float*)(ws + o_pool);
    float* s1 = (float*)(ws + o_stats);
    float* q1 = s1 + 128;
    float* s2 = q1 + 128;
    float* q2 = s2 + 64;
    float* s3 = q2 + 64;
    float* q3 = s3 + 32;
    float* a1 = (float*)(ws + o_aff);
    float* c1 = a1 + 128;
    float* a2 = c1 + 128;
    float* c2 = a2 + 64;
    float* a3 = c2 + 64;
    float* c3 = a3 + 32;
    float* cv1r = (float*)(ws + o_cvec);
    float* cvdum = cv1r + 128;
    float* cv2l = cvdum + 128;
    float* cv2r = cv2l + 64;
    float* cv3l = cv2r + 64;
    float* cv3r = cv3l + 32;
    short* W1l_t = (short*)(ws + o_wt);          // 128x64
    short* W1r_t = W1l_t + 8192;                 // 128x64
    short* W2l_t = W1r_t + 8192;                 // 64x128
    short* W2r_t = W2l_t + 8192;                 // 64x128
    short* W3l_t = W2r_t + 8192;                 // 32x64
    short* W3r_t = W3l_t + 2048;                 // 32x64

    const float invN = 1.0f / (float)N;
    const int MG = 512;  // k_mgemm grid

    // ---- zero accumulators ----
    hipMemsetAsync(ws + o_hist, 0, (size_t)N * 4, stream);
    hipMemsetAsync(ws + o_stats, 0, 448 * 4, stream);
    hipMemsetAsync(ws + o_pool, 0, (size_t)NGRAPH * 32 * 4, stream);

    // ---- CSR build ----
    k_hist<<<2048, 256, 0, stream>>>(dst, hist, E);
    k_scan<<<1, 1024, 0, stream>>>(hist, row_off, cursor, N);
    k_scatter<<<2048, 256, 0, stream>>>(src, dst, cursor, csr, E);

    // ---- prep: x->bf16, layer-1 weights ----
    k_cvt<<<(int)(((long long)N * 16 + 255) / 256), 256, 0, stream>>>(
        x, xb, (long long)N * 16);
    k_wprep<64, 128, false><<<2, 64, 0, stream>>>(
        W1r, nullptr, nullptr, b1, W1r_t, cv1r);
    k_wprep<64, 128, false><<<2, 64, 0, stream>>>(
        W1l, nullptr, nullptr, nullptr, W1l_t, cvdum);

    // ---- layer 1: t1 = relu(x@W1r + invc*(agg@W1l) + b1) ----
    k_gather<64, true><<<(N + 15) / 16, 256, 0, stream>>>(
        x, row_off, csr, aggb, N);
    k_mgemm<64, 128, true, false, true, true><<<MG, 256, 0, stream>>>(
        xb, aggb, W1r_t, W1l_t, cv1r, nullptr, row_off, t1b, s1, q1, N);
    k_finalize<<<1, 128, 0, stream>>>(s1, q1, g1, be1, a1, c1, 128, invN);

    // ---- layer 2 ----
    k_wprep<128, 64, true><<<1, 64, 0, stream>>>(W2l, a1, c1, nullptr, W2l_t, cv2l);
    k_wprep<128, 64, true><<<1, 64, 0, stream>>>(W2r, a1, c1, b2, W2r_t, cv2r);
    // y2 = t1_eff @ W2l + cv2l   (fp32)
    k_mgemm<128, 64, false, false, false, false><<<MG, 256, 0, stream>>>(
        t1b, nullptr, W2l_t, nullptr, cv2l, nullptr, row_off, y2,
        nullptr, nullptr, N);
    k_gather<64, false><<<(N + 15) / 16, 256, 0, stream>>>(
        y2, row_off, csr, m2, N);
    // t2 = relu(t1_eff @ W2r + invc*m2 + cv2r)   (bf16 out + stats)
    k_mgemm<128, 64, false, true, true, true><<<MG, 256, 0, stream>>>(
        t1b, nullptr, W2r_t, nullptr, cv2r, m2, row_off, t2b, s2, q2, N);
    k_finalize<<<1, 64, 0, stream>>>(s2, q2, g2, be2, a2, c2, 64, invN);

    // ---- layer 3 ----
    k_wprep<64, 32, true><<<1, 64, 0, stream>>>(W3l, a2, c2, nullptr, W3l_t, cv3l);
    k_wprep<64, 32, true><<<1, 64, 0, stream>>>(W3r, a2, c2, b3, W3r_t, cv3r);
    k_mgemm<64, 32, false, false, false, false><<<MG, 256, 0, stream>>>(
        t2b, nullptr, W3l_t, nullptr, cv3l, nullptr, row_off, y3,
        nullptr, nullptr, N);
    k_gather<32, false><<<(N + 31) / 32, 256, 0, stream>>>(
        y3, row_off, csr, m3, N);
    // t3 = relu(t2_eff @ W3r + invc*m3 + cv3r)   (fp32 out + stats)
    k_mgemm<64, 32, false, true, true, false><<<MG, 256, 0, stream>>>(
        t2b, nullptr, W3r_t, nullptr, cv3r, m3, row_off, t3, s3, q3, N);
    k_finalize<<<1, 32, 0, stream>>>(s3, q3, g3, be3, a3, c3, 32, invN);

    // ---- pool + MLP ----
    {
        long long tot = (long long)N * 32;
        int blocks = (int)((tot + 255) / 256);
        k_pool<<<blocks, 256, 0, stream>>>(t3, a3, c3, batch, pooled, N);
    }
    k_mlp<<<NGRAPH, 128, 0, stream>>>(pooled, Wf1, bf1, Wf2, bf2, Wf3, bf3,
                                      (float*)d_out);
}

// Round 6
// 312.367 us; speedup vs baseline: 4.2478x; 1.4629x over previous
//
#include <hip/hip_runtime.h>
#include <hip/hip_bf16.h>

#define EPSBN 1e-5f
#define NGRAPH 512
#define SCAN_NB 128

typedef __attribute__((ext_vector_type(8))) short bf16x8;
typedef __attribute__((ext_vector_type(4))) float f32x4;

__device__ inline short f2bf(float f) {  // RNE float->bf16
    unsigned u = __builtin_bit_cast(unsigned, f);
    u += 0x7fffu + ((u >> 16) & 1u);
    return (short)(u >> 16);
}
__device__ inline float bf2f(short s) {
    unsigned u = ((unsigned)(unsigned short)s) << 16;
    return __builtin_bit_cast(float, u);
}

// ---------------------------------------------------------------------------
// CSR build
// ---------------------------------------------------------------------------
__global__ void __launch_bounds__(256) k_hist(
    const int* __restrict__ dst, int* __restrict__ hist, int E)
{
    for (int e = blockIdx.x * 256 + threadIdx.x; e < E; e += gridDim.x * 256)
        atomicAdd(&hist[dst[e]], 1);
}

// scan phase 1: per-block partial sums of hist
__global__ void __launch_bounds__(256) k_scan1(
    const int* __restrict__ hist, int* __restrict__ blocksum, int N)
{
    __shared__ int red[256];
    const int C = (N + SCAN_NB - 1) / SCAN_NB;
    const int b = blockIdx.x, t = threadIdx.x;
    const int lo = b * C, hi = min(lo + C, N);
    int s = 0;
    for (int i = lo + t; i < hi; i += 256) s += hist[i];
    red[t] = s;
    __syncthreads();
    for (int off = 128; off; off >>= 1) {
        if (t < off) red[t] += red[t + off];
        __syncthreads();
    }
    if (t == 0) blocksum[b] = red[0];
}

// scan phase 2: exclusive scan of 128 block sums; writes row_off[N]
__global__ void __launch_bounds__(SCAN_NB) k_scan2(
    const int* __restrict__ blocksum, int* __restrict__ blockoff,
    int* __restrict__ row_off, int N)
{
    __shared__ int tmp[SCAN_NB];
    const int t = threadIdx.x;
    int v = blocksum[t];
    tmp[t] = v;
    __syncthreads();
    for (int off = 1; off < SCAN_NB; off <<= 1) {
        int u = (t >= off) ? tmp[t - off] : 0;
        __syncthreads();
        tmp[t] += u;
        __syncthreads();
    }
    blockoff[t] = tmp[t] - v;
    if (t == SCAN_NB - 1) row_off[N] = tmp[t];
}

// scan phase 3: per-block local exclusive scan + global offset
__global__ void __launch_bounds__(256) k_scan3(
    const int* __restrict__ hist, const int* __restrict__ blockoff,
    int* __restrict__ row_off, int* __restrict__ cursor, int N)
{
    __shared__ int red[256];
    const int C = (N + SCAN_NB - 1) / SCAN_NB;
    const int b = blockIdx.x, t = threadIdx.x;
    const int lo = b * C, hi = min(lo + C, N);
    const int TC = (C + 255) / 256;
    const int s0 = lo + t * TC;
    const int s1 = min(s0 + TC, hi);
    int s = 0;
    for (int i = s0; i < s1; i++) s += hist[i];
    red[t] = s;
    __syncthreads();
    for (int off = 1; off < 256; off <<= 1) {
        int u = (t >= off) ? red[t - off] : 0;
        __syncthreads();
        red[t] += u;
        __syncthreads();
    }
    int run = blockoff[b] + red[t] - s;
    for (int i = s0; i < s1; i++) {
        row_off[i] = run;
        cursor[i] = run;
        run += hist[i];
    }
}

__global__ void __launch_bounds__(256) k_scatter(
    const int* __restrict__ src, const int* __restrict__ dst,
    int* __restrict__ cursor, int* __restrict__ csr, int E)
{
    for (int e = blockIdx.x * 256 + threadIdx.x; e < E; e += gridDim.x * 256) {
        int d = dst[e];
        int p = atomicAdd(&cursor[d], 1);
        csr[p] = src[e];
    }
}

// ---------------------------------------------------------------------------
// Gather-aggregate, bf16 input rows (16B/lane), fp32 accumulate,
// bf16 (OB=1) or fp32 (OB=0) output.
// ---------------------------------------------------------------------------
template <int F, bool OB>
__global__ void __launch_bounds__(256) k_gatherb(
    const short* __restrict__ feat, const int* __restrict__ row_off,
    const int* __restrict__ csr, void* __restrict__ aggv, int N)
{
    constexpr int LPR = F / 8;        // lanes per row
    constexpr int RPB = 256 / LPR;    // rows per block
    const int lane = threadIdx.x % LPR;
    const int rloc = threadIdx.x / LPR;
    float* aggf = (float*)aggv;
    short* aggb = (short*)aggv;
    for (int row = blockIdx.x * RPB + rloc; row < N; row += gridDim.x * RPB) {
        const int s0 = row_off[row];
        const int s1 = row_off[row + 1];
        float acc0[8], acc1[8];
        #pragma unroll
        for (int i = 0; i < 8; i++) { acc0[i] = 0.f; acc1[i] = 0.f; }
        int p = s0;
        for (; p + 1 < s1; p += 2) {
            int sA = csr[p];
            int sB = csr[p + 1];
            bf16x8 va = *(const bf16x8*)&feat[(long long)sA * F + lane * 8];
            bf16x8 vb = *(const bf16x8*)&feat[(long long)sB * F + lane * 8];
            #pragma unroll
            for (int i = 0; i < 8; i++) {
                acc0[i] += bf2f(va[i]);
                acc1[i] += bf2f(vb[i]);
            }
        }
        if (p < s1) {
            int sA = csr[p];
            bf16x8 va = *(const bf16x8*)&feat[(long long)sA * F + lane * 8];
            #pragma unroll
            for (int i = 0; i < 8; i++) acc0[i] += bf2f(va[i]);
        }
        if constexpr (OB) {
            short o[8];
            #pragma unroll
            for (int i = 0; i < 8; i++) o[i] = f2bf(acc0[i] + acc1[i]);
            *(bf16x8*)&aggb[(long long)row * F + lane * 8] = *(bf16x8*)o;
        } else {
            float4 o0 = make_float4(acc0[0] + acc1[0], acc0[1] + acc1[1],
                                    acc0[2] + acc1[2], acc0[3] + acc1[3]);
            float4 o1 = make_float4(acc0[4] + acc1[4], acc0[5] + acc1[5],
                                    acc0[6] + acc1[6], acc0[7] + acc1[7]);
            *(float4*)&aggf[(long long)row * F + lane * 8] = o0;
            *(float4*)&aggf[(long long)row * F + lane * 8 + 4] = o1;
        }
    }
}

// ---------------------------------------------------------------------------
// fp32 -> bf16 convert
// ---------------------------------------------------------------------------
__global__ void __launch_bounds__(256) k_cvt(
    const float* __restrict__ in, short* __restrict__ out, long long n4)
{
    long long i = (long long)blockIdx.x * 256 + threadIdx.x;
    if (i >= n4) return;
    float4 v = *(const float4*)&in[i * 4];
    short4 o = make_short4(f2bf(v.x), f2bf(v.y), f2bf(v.z), f2bf(v.w));
    *(short4*)&out[i * 4] = o;
}

// ---------------------------------------------------------------------------
// Weight prep: Wt[j][k] = bf16(a[k]*W[k][j]); cvec[j] = sum_k c[k]*W[k][j] + bias[j]
// ---------------------------------------------------------------------------
template <int K, int F, bool AFF>
__global__ void __launch_bounds__(64) k_wprep(
    const float* __restrict__ W, const float* __restrict__ a,
    const float* __restrict__ c, const float* __restrict__ bias,
    short* __restrict__ Wt, float* __restrict__ cvec)
{
    int j = blockIdx.x * 64 + threadIdx.x;
    if (j >= F) return;
    float cv = bias ? bias[j] : 0.f;
    for (int k = 0; k < K; k++) {
        float w = W[k * F + j];
        float aa = 1.f;
        if constexpr (AFF) {
            aa = a[k];
            cv += c[k] * w;
        }
        Wt[j * K + k] = f2bf(aa * w);
    }
    cvec[j] = cv;
}

// ---------------------------------------------------------------------------
// MFMA bf16 GEMM with fused epilogue.
//   out = [relu]( A@Wt' + DUAL*invc*(A2@Wt2') + HASBASE*invc*base + cvec )
// ---------------------------------------------------------------------------
template <int K, int FOUT, bool DUAL, bool HASBASE, bool FINAL, bool OUTBF16>
__global__ void __launch_bounds__(256) k_mgemm(
    const short* __restrict__ A, const short* __restrict__ A2,
    const short* __restrict__ Wt, const short* __restrict__ Wt2,
    const float* __restrict__ cvec, const float* __restrict__ base,
    const int* __restrict__ row_off, void* outv,
    float* __restrict__ s_out, float* __restrict__ q_out, int N)
{
    constexpr int KS = K / 32;
    constexpr int NCT = FOUT / 16;
    const int lane = threadIdx.x & 63;
    const int wid = threadIdx.x >> 6;
    const int g = lane >> 4;
    const int mi = lane & 15;
    const int RT = (N + 15) >> 4;
    const int nw = gridDim.x * 4;
    float* outf = (float*)outv;
    short* outb = (short*)outv;

    float st_s[FINAL ? NCT : 1];
    float st_q[FINAL ? NCT : 1];
    if constexpr (FINAL) {
        #pragma unroll
        for (int ct = 0; ct < NCT; ct++) { st_s[ct] = 0.f; st_q[ct] = 0.f; }
    }

    for (int rt = blockIdx.x * 4 + wid; rt < RT; rt += nw) {
        const int m0 = rt * 16;
        int arow = m0 + mi;
        if (arow >= N) arow = N - 1;

        bf16x8 af[KS];
        bf16x8 af2[DUAL ? KS : 1];
        const short* ap = A + (long long)arow * K;
        #pragma unroll
        for (int s = 0; s < KS; s++)
            af[s] = *(const bf16x8*)(ap + s * 32 + g * 8);
        if constexpr (DUAL) {
            const short* ap2 = A2 + (long long)arow * K;
            #pragma unroll
            for (int s = 0; s < KS; s++)
                af2[s] = *(const bf16x8*)(ap2 + s * 32 + g * 8);
        }

        float invc[4];
        if constexpr (DUAL || HASBASE) {
            #pragma unroll
            for (int r = 0; r < 4; r++) {
                int row = m0 + 4 * g + r;
                int cnt = 1;
                if (row < N) cnt = max(row_off[row + 1] - row_off[row], 1);
                invc[r] = 1.f / (float)cnt;
            }
        }

        #pragma unroll
        for (int ct = 0; ct < NCT; ct++) {
            f32x4 acc = {0.f, 0.f, 0.f, 0.f};
            f32x4 acc2 = {0.f, 0.f, 0.f, 0.f};
            const short* bp = Wt + (long long)(ct * 16 + mi) * K;
            #pragma unroll
            for (int s = 0; s < KS; s++) {
                bf16x8 bf = *(const bf16x8*)(bp + s * 32 + g * 8);
                acc = __builtin_amdgcn_mfma_f32_16x16x32_bf16(af[s], bf, acc, 0, 0, 0);
                if constexpr (DUAL) {
                    bf16x8 bf2 = *(const bf16x8*)(Wt2 + (long long)(ct * 16 + mi) * K + s * 32 + g * 8);
                    acc2 = __builtin_amdgcn_mfma_f32_16x16x32_bf16(af2[s], bf2, acc2, 0, 0, 0);
                }
            }
            float cv = cvec[ct * 16 + mi];
            float sl = 0.f, ql = 0.f;
            #pragma unroll
            for (int r = 0; r < 4; r++) {
                int row = m0 + 4 * g + r;
                if (row < N) {
                    float v = acc[r] + cv;
                    if constexpr (DUAL) v = fmaf(invc[r], acc2[r], v);
                    if constexpr (HASBASE)
                        v = fmaf(invc[r], base[(long long)row * FOUT + ct * 16 + mi], v);
                    if constexpr (FINAL) v = fmaxf(v, 0.f);
                    if constexpr (OUTBF16)
                        outb[(long long)row * FOUT + ct * 16 + mi] = f2bf(v);
                    else
                        outf[(long long)row * FOUT + ct * 16 + mi] = v;
                    if constexpr (FINAL) { sl += v; ql += v * v; }
                }
            }
            if constexpr (FINAL) {
                sl += __shfl_xor(sl, 16, 64);
                sl += __shfl_xor(sl, 32, 64);
                ql += __shfl_xor(ql, 16, 64);
                ql += __shfl_xor(ql, 32, 64);
                st_s[ct] += sl;
                st_q[ct] += ql;
            }
        }
    }

    if constexpr (FINAL) {
        __shared__ float redS[4][NCT][16];
        __shared__ float redQ[4][NCT][16];
        if (lane < 16) {
            #pragma unroll
            for (int ct = 0; ct < NCT; ct++) {
                redS[wid][ct][lane] = st_s[ct];
                redQ[wid][ct][lane] = st_q[ct];
            }
        }
        __syncthreads();
        if (wid == 0 && lane < 16) {
            #pragma unroll
            for (int ct = 0; ct < NCT; ct++) {
                float s = redS[0][ct][lane] + redS[1][ct][lane] +
                          redS[2][ct][lane] + redS[3][ct][lane];
                float q = redQ[0][ct][lane] + redQ[1][ct][lane] +
                          redQ[2][ct][lane] + redQ[3][ct][lane];
                atomicAdd(&s_out[ct * 16 + lane], s);
                atomicAdd(&q_out[ct * 16 + lane], q);
            }
        }
    }
}

// ---------------------------------------------------------------------------
// BN affine finalize
// ---------------------------------------------------------------------------
__global__ void k_finalize(const float* __restrict__ s, const float* __restrict__ q,
                           const float* __restrict__ g, const float* __restrict__ be,
                           float* __restrict__ a, float* __restrict__ c,
                           int F, float invN)
{
    int j = threadIdx.x;
    if (j < F) {
        float mu = s[j] * invN;
        float var = q[j] * invN - mu * mu;
        float aj = g[j] / sqrtf(var + EPSBN);
        a[j] = aj;
        c[j] = be[j] - mu * aj;
    }
}

// ---------------------------------------------------------------------------
// pooled[batch[i]][j] += t3[i][j]*a[j] + c[j]
// ---------------------------------------------------------------------------
__global__ void __launch_bounds__(256) k_pool(
    const float* __restrict__ t3, const float* __restrict__ a,
    const float* __restrict__ c, const int* __restrict__ batch,
    float* __restrict__ pooled, int N)
{
    long long gid = (long long)blockIdx.x * 256 + threadIdx.x;
    int i = (int)(gid >> 5);
    int j = (int)(gid & 31);
    if (i >= N) return;
    int g = batch[i];
    float v = t3[(long long)i * 32 + j] * a[j] + c[j];
    atomicAdd(&pooled[g * 32 + j], v);
}

// ---------------------------------------------------------------------------
// Per-graph MLP
// ---------------------------------------------------------------------------
__global__ void __launch_bounds__(128) k_mlp(
    const float* __restrict__ pooled,
    const float* __restrict__ Wf1, const float* __restrict__ bf1,
    const float* __restrict__ Wf2, const float* __restrict__ bf2,
    const float* __restrict__ Wf3, const float* __restrict__ bf3,
    float* __restrict__ out)
{
    __shared__ float p[32], h1[128], h2[64];
    int g = blockIdx.x, t = threadIdx.x;
    if (t < 32) p[t] = pooled[g * 32 + t];
    __syncthreads();
    {
        float acc = bf1[t];
        #pragma unroll
        for (int k = 0; k < 32; k++) acc += p[k] * Wf1[k * 128 + t];
        h1[t] = fmaxf(acc, 0.f);
    }
    __syncthreads();
    if (t < 64) {
        float acc = bf2[t];
        #pragma unroll
        for (int k = 0; k < 128; k++) acc += h1[k] * Wf2[k * 64 + t];
        h2[t] = fmaxf(acc, 0.f);
    }
    __syncthreads();
    if (t < 2) {
        float acc = bf3[t];
        #pragma unroll
        for (int k = 0; k < 64; k++) acc += h2[k] * Wf3[k * 2 + t];
        out[g * 2 + t] = acc;
    }
}

// ---------------------------------------------------------------------------
extern "C" void kernel_launch(void* const* d_in, const int* in_sizes, int n_in,
                              void* d_out, int out_size, void* d_ws, size_t ws_size,
                              hipStream_t stream)
{
    const float* x     = (const float*)d_in[0];
    const int*   ei    = (const int*)d_in[1];
    const int*   batch = (const int*)d_in[2];
    const float* W1l = (const float*)d_in[3];
    const float* b1  = (const float*)d_in[4];
    const float* W1r = (const float*)d_in[5];
    const float* g1  = (const float*)d_in[6];
    const float* be1 = (const float*)d_in[7];
    const float* W2l = (const float*)d_in[8];
    const float* b2  = (const float*)d_in[9];
    const float* W2r = (const float*)d_in[10];
    const float* g2  = (const float*)d_in[11];
    const float* be2 = (const float*)d_in[12];
    const float* W3l = (const float*)d_in[13];
    const float* b3  = (const float*)d_in[14];
    const float* W3r = (const float*)d_in[15];
    const float* g3  = (const float*)d_in[16];
    const float* be3 = (const float*)d_in[17];
    const float* Wf1 = (const float*)d_in[18];
    const float* bf1 = (const float*)d_in[19];
    const float* Wf2 = (const float*)d_in[20];
    const float* bf2 = (const float*)d_in[21];
    const float* Wf3 = (const float*)d_in[22];
    const float* bf3 = (const float*)d_in[23];

    const int N = in_sizes[0] / 64;
    const int E = in_sizes[1] / 2;
    const int* src = ei;
    const int* dst = ei + E;

    // ---- workspace layout (zoned aliasing) ----
    char* ws = (char*)d_ws;
    size_t off = 0;
    auto alloc = [&](size_t bytes) {
        size_t o = off;
        off += (bytes + 511) & ~(size_t)511;
        return o;
    };
    const size_t o_rowoff = alloc((size_t)(N + 1) * 4);
    const size_t o_hist   = alloc((size_t)N * 4);
    const size_t o_cursor = alloc((size_t)N * 4);
    const size_t o_bsum   = alloc(SCAN_NB * 4 * 2);
    const size_t o_csr    = alloc((size_t)E * 4);
    const size_t o_zoneB  = alloc((size_t)N * 128);  // xb -> y2b (bf16)
    const size_t o_zoneC  = alloc((size_t)N * 128);  // aggb -> t2b (bf16)
    const size_t o_zoneD  = alloc((size_t)N * 256);  // t1b (bf16) -> y3b (bf16)
    const size_t o_zoneE  = alloc((size_t)N * 256);  // m2 (fp32) -> m3/t3 (fp32)
    const size_t o_pool   = alloc((size_t)NGRAPH * 32 * 4);
    const size_t o_stats  = alloc(448 * 4);
    const size_t o_aff    = alloc(448 * 4);
    const size_t o_cvec   = alloc(512 * 4);
    const size_t o_wt     = alloc((8192 * 4 + 2048 * 2) * 2);
    (void)ws_size;

    int* row_off = (int*)(ws + o_rowoff);
    int* hist    = (int*)(ws + o_hist);
    int* cursor  = (int*)(ws + o_cursor);
    int* bsum    = (int*)(ws + o_bsum);
    int* boff    = bsum + SCAN_NB;
    int* csr     = (int*)(ws + o_csr);
    short* xb   = (short*)(ws + o_zoneB);
    short* y2b  = (short*)(ws + o_zoneB);       // after xb dead (post-mgemm1)
    short* aggb = (short*)(ws + o_zoneC);
    short* t2b  = (short*)(ws + o_zoneC);       // after aggb dead
    short* t1b  = (short*)(ws + o_zoneD);
    short* y3b  = (short*)(ws + o_zoneD);       // after t1b dead (post-mgemm2)
    float* m2   = (float*)(ws + o_zoneE);
    float* m3   = (float*)(ws + o_zoneE);       // after m2 dead
    float* t3   = m3;                           // in-place epilogue overwrite
    float* pooled = (float*)(ws + o_pool);
    float* s1 = (float*)(ws + o_stats);
    float* q1 = s1 + 128;
    float* s2 = q1 + 128;
    float* q2 = s2 + 64;
    float* s3 = q2 + 64;
    float* q3 = s3 + 32;
    float* a1 = (float*)(ws + o_aff);
    float* c1 = a1 + 128;
    float* a2 = c1 + 128;
    float* c2 = a2 + 64;
    float* a3 = c2 + 64;
    float* c3 = a3 + 32;
    float* cv1r = (float*)(ws + o_cvec);
    float* cvdum = cv1r + 128;
    float* cv2l = cvdum + 128;
    float* cv2r = cv2l + 64;
    float* cv3l = cv2r + 64;
    float* cv3r = cv3l + 32;
    short* W1l_t = (short*)(ws + o_wt);          // 128x64
    short* W1r_t = W1l_t + 8192;                 // 128x64
    short* W2l_t = W1r_t + 8192;                 // 64x128
    short* W2r_t = W2l_t + 8192;                 // 64x128
    short* W3l_t = W2r_t + 8192;                 // 32x64
    short* W3r_t = W3l_t + 2048;                 // 32x64

    const float invN = 1.0f / (float)N;
    const int MG = 512;  // k_mgemm grid

    // ---- zero accumulators ----
    hipMemsetAsync(ws + o_hist, 0, (size_t)N * 4, stream);
    hipMemsetAsync(ws + o_stats, 0, 448 * 4, stream);
    hipMemsetAsync(ws + o_pool, 0, (size_t)NGRAPH * 32 * 4, stream);

    // ---- CSR build (hierarchical scan) ----
    k_hist<<<2048, 256, 0, stream>>>(dst, hist, E);
    k_scan1<<<SCAN_NB, 256, 0, stream>>>(hist, bsum, N);
    k_scan2<<<1, SCAN_NB, 0, stream>>>(bsum, boff, row_off, N);
    k_scan3<<<SCAN_NB, 256, 0, stream>>>(hist, boff, row_off, cursor, N);
    k_scatter<<<2048, 256, 0, stream>>>(src, dst, cursor, csr, E);

    // ---- prep: x->bf16, layer-1 weights ----
    k_cvt<<<(int)(((long long)N * 16 + 255) / 256), 256, 0, stream>>>(
        x, xb, (long long)N * 16);
    k_wprep<64, 128, false><<<2, 64, 0, stream>>>(
        W1r, nullptr, nullptr, b1, W1r_t, cv1r);
    k_wprep<64, 128, false><<<2, 64, 0, stream>>>(
        W1l, nullptr, nullptr, nullptr, W1l_t, cvdum);

    // ---- layer 1: t1 = relu(x@W1r + invc*(agg@W1l) + b1) ----
    k_gatherb<64, true><<<(N + 31) / 32, 256, 0, stream>>>(
        xb, row_off, csr, aggb, N);
    k_mgemm<64, 128, true, false, true, true><<<MG, 256, 0, stream>>>(
        xb, aggb, W1r_t, W1l_t, cv1r, nullptr, row_off, t1b, s1, q1, N);
    k_finalize<<<1, 128, 0, stream>>>(s1, q1, g1, be1, a1, c1, 128, invN);

    // ---- layer 2 ----
    k_wprep<128, 64, true><<<1, 64, 0, stream>>>(W2l, a1, c1, nullptr, W2l_t, cv2l);
    k_wprep<128, 64, true><<<1, 64, 0, stream>>>(W2r, a1, c1, b2, W2r_t, cv2r);
    // y2b = bf16(t1_eff @ W2l + cv2l)
    k_mgemm<128, 64, false, false, false, true><<<MG, 256, 0, stream>>>(
        t1b, nullptr, W2l_t, nullptr, cv2l, nullptr, row_off, y2b,
        nullptr, nullptr, N);
    k_gatherb<64, false><<<(N + 31) / 32, 256, 0, stream>>>(
        y2b, row_off, csr, m2, N);
    // t2 = relu(t1_eff @ W2r + invc*m2 + cv2r)   (bf16 out + stats)
    k_mgemm<128, 64, false, true, true, true><<<MG, 256, 0, stream>>>(
        t1b, nullptr, W2r_t, nullptr, cv2r, m2, row_off, t2b, s2, q2, N);
    k_finalize<<<1, 64, 0, stream>>>(s2, q2, g2, be2, a2, c2, 64, invN);

    // ---- layer 3 ----
    k_wprep<64, 32, true><<<1, 64, 0, stream>>>(W3l, a2, c2, nullptr, W3l_t, cv3l);
    k_wprep<64, 32, true><<<1, 64, 0, stream>>>(W3r, a2, c2, b3, W3r_t, cv3r);
    k_mgemm<64, 32, false, false, false, true><<<MG, 256, 0, stream>>>(
        t2b, nullptr, W3l_t, nullptr, cv3l, nullptr, row_off, y3b,
        nullptr, nullptr, N);
    k_gatherb<32, false><<<(N + 63) / 64, 256, 0, stream>>>(
        y3b, row_off, csr, m3, N);
    // t3 = relu(t2_eff @ W3r + invc*m3 + cv3r)   (fp32 out + stats, in place)
    k_mgemm<64, 32, false, true, true, false><<<MG, 256, 0, stream>>>(
        t2b, nullptr, W3r_t, nullptr, cv3r, m3, row_off, t3, s3, q3, N);
    k_finalize<<<1, 32, 0, stream>>>(s3, q3, g3, be3, a3, c3, 32, invN);

    // ---- pool + MLP ----
    {
        long long tot = (long long)N * 32;
        int blocks = (int)((tot + 255) / 256);
        k_pool<<<blocks, 256, 0, stream>>>(t3, a3, c3, batch, pooled, N);
    }
    k_mlp<<<NGRAPH, 128, 0, stream>>>(pooled, Wf1, bf1, Wf2, bf2, Wf3, bf3,
                                      (float*)d_out);
}